// Round 10
// baseline (6506.675 us; speedup 1.0000x reference)
//
#include <hip/hip_runtime.h>
#include <math.h>

#define T_STEPS 512
#define BATCH   64
#define INDIM   512
#define MEMDIM  512
#define NWG     256
#define NT      1024

// WG wg owns mem dims {2wg,2wg+1} (8 gate rows). Weights LDS-stationary.
// h exchange: transposed single-writer ws buffer hist[2][512][64] (relaxed
// agent-scope atomics; no false sharing; coalesced lane=batch reads).
// out[t][b][m] stores DEFERRED past the arrive (drain next step).
// x-dot hoisted above the epoch wait.
// NEW (R10): RMW-FREE barrier. Arrive = one relaxed store to bar[wg]
// (256 distinct dwords). Wait = wave 0 polls all 256 slots (64 lanes x
// 2 u64 loads), min-reduce + __all. One memory round trip, no tree hops.
// LDS (dynamic, 77KB): W_s[8][1028] | xpart[4][8][68] | hpart[16][8][68]
//                      | c_s[2][64] | bias_s[8]

#define SMEM_FLOATS (8*1028 + 4*8*68 + 16*8*68 + 2*64 + 8)

extern "C" __global__ void __launch_bounds__(NT, 1)
lstm_scan(const float* __restrict__ inputs, const float* __restrict__ h0,
          const float* __restrict__ c0,
          const float* __restrict__ W_ioux, const float* __restrict__ b_ioux,
          const float* __restrict__ W_iouh, const float* __restrict__ b_iouh,
          const float* __restrict__ W_fx,   const float* __restrict__ b_fx,
          const float* __restrict__ W_fh,   const float* __restrict__ b_fh,
          float* __restrict__ out, int* __restrict__ bar)
{
    extern __shared__ float smem[];
    float* W_s    = smem;                       // [8][1028]
    float* xpart  = smem + 8*1028;              // [4][8][68]
    float* hpart  = xpart + 4*8*68;             // [16][8][68]
    float* c_s    = hpart + 16*8*68;            // [2][64]
    float* bias_s = c_s + 2*64;                 // [8]

    float* hist = (float*)(bar + 2048);         // [2][512][64] at ws+8KB

    const int tid  = threadIdx.x;
    const int wg   = blockIdx.x;
    const int lane = tid & 63;
    const int wv16 = tid >> 6;          // wave 0..15

    // x-dot mapping: quarter q, gate row j8, batch rows b0,b1
    const int q    = tid >> 8;
    const int r    = tid & 255;
    const int j8   = r & 7;
    const int bsub = (r >> 3) & 7;
    const int wv   = r >> 6;
    const int b0   = 16 * wv + bsub;
    const int b1   = b0 + 8;

    // h-dot mapping: wave owns dims [32*wv16, 32*wv16+32); lane=batch pair
    const int s    = lane & 31;         // batch pair index
    const int dsub = lane >> 5;         // 0/1

    // ---- stage weights into LDS (once) ----
    for (int i = tid; i < 8 * 256; i += NT) {
        int row = i >> 8;
        int c4  = i & 255;
        int mloc = row >> 2, gate = row & 3;
        int mg = 2 * wg + mloc;
        const float* src;
        if (c4 < 128) {
            const float* Wx = (gate < 3) ? (W_ioux + (size_t)(gate * 512 + mg) * INDIM)
                                         : (W_fx   + (size_t)mg * INDIM);
            src = Wx + c4 * 4;
        } else {
            const float* Wh = (gate < 3) ? (W_iouh + (size_t)(gate * 512 + mg) * MEMDIM)
                                         : (W_fh   + (size_t)mg * MEMDIM);
            src = Wh + (c4 - 128) * 4;
        }
        float4 v = *(const float4*)src;
        *(float4*)&W_s[row * 1028 + c4 * 4] = v;
    }
    if (tid < 8) {
        int mloc = tid >> 2, gate = tid & 3, mg = 2 * wg + mloc;
        bias_s[tid] = (gate < 3) ? (b_ioux[gate * 512 + mg] + b_iouh[gate * 512 + mg])
                                 : (b_fx[mg] + b_fh[mg]);
    }
    if (tid < 128) {
        int mloc = tid >> 6, b = tid & 63;
        c_s[mloc * 64 + b] = c0[(size_t)b * MEMDIM + 2 * wg + mloc];
        // prologue: transpose h0 slice into hist[0] (single-writer rows)
        float hv = h0[(size_t)b * MEMDIM + 2 * wg + mloc];
        __hip_atomic_store(&hist[(2 * wg + mloc) * 64 + b], hv,
                           __ATOMIC_RELAXED, __HIP_MEMORY_SCOPE_AGENT);
    }
    __syncthreads();   // LDS ready; hist[0] stores drained (vmcnt)

    if (tid == 0) {    // arrive epoch 1 (hist[0] ready): single store, no RMW
        __hip_atomic_store(&bar[wg], 1, __ATOMIC_RELAXED, __HIP_MEMORY_SCOPE_AGENT);
    }

    const float4* wrowx = (const float4*)&W_s[j8 * 1028] + q * 32;

    for (int t = 0; t < T_STEPS; ++t) {
        // ---- x-side dot (independent of h; overlaps the wait) ----
        const float4* x0p = (const float4*)(inputs + ((size_t)t * BATCH + b0) * INDIM) + q * 32;
        const float4* x1p = (const float4*)(inputs + ((size_t)t * BATCH + b1) * INDIM) + q * 32;
        float4 a0 = make_float4(0.f, 0.f, 0.f, 0.f);
        float4 a1 = make_float4(0.f, 0.f, 0.f, 0.f);
#pragma unroll 8
        for (int k = 0; k < 32; ++k) {
            float4 w  = wrowx[k];
            float4 v0 = x0p[k];
            float4 v1 = x1p[k];
            a0.x += v0.x * w.x; a0.y += v0.y * w.y; a0.z += v0.z * w.z; a0.w += v0.w * w.w;
            a1.x += v1.x * w.x; a1.y += v1.y * w.y; a1.z += v1.z * w.z; a1.w += v1.w * w.w;
        }
        xpart[q * 544 + j8 * 68 + b0] = a0.x + a0.y + a0.z + a0.w;
        xpart[q * 544 + j8 * 68 + b1] = a1.x + a1.y + a1.z + a1.w;

        // ---- wait for epoch t+1: wave 0 polls all 256 slots directly ----
        if (tid < 64) {
            const unsigned long long* slots = (const unsigned long long*)bar;
            const int need = t + 1;
            for (;;) {
                unsigned long long v0 = __hip_atomic_load(slots + 2 * tid,
                                                          __ATOMIC_RELAXED,
                                                          __HIP_MEMORY_SCOPE_AGENT);
                unsigned long long v1 = __hip_atomic_load(slots + 2 * tid + 1,
                                                          __ATOMIC_RELAXED,
                                                          __HIP_MEMORY_SCOPE_AGENT);
                int e0 = (int)(unsigned)(v0 & 0xffffffffULL);
                int e1 = (int)(unsigned)(v0 >> 32);
                int e2 = (int)(unsigned)(v1 & 0xffffffffULL);
                int e3 = (int)(unsigned)(v1 >> 32);
                int m0 = e0 < e1 ? e0 : e1;
                int m1 = e2 < e3 ? e2 : e3;
                int mn = m0 < m1 ? m0 : m1;
                if (__all(mn >= need)) break;
                __builtin_amdgcn_s_sleep(1);
            }
        }
        __syncthreads();

        // ---- h-side dot: wave-owned 32-dim slice, lane=batch, coalesced ----
        const unsigned long long* hrow =
            (const unsigned long long*)(hist + (size_t)(t & 1) * 32768);
        float2 hacc[8];
#pragma unroll
        for (int j = 0; j < 8; ++j) { hacc[j].x = 0.f; hacc[j].y = 0.f; }
#pragma unroll 4
        for (int it = 0; it < 16; ++it) {
            int d = wv16 * 32 + it * 2 + dsub;
            unsigned long long u = __hip_atomic_load(hrow + d * 32 + s,
                                                     __ATOMIC_RELAXED,
                                                     __HIP_MEMORY_SCOPE_AGENT);
            float2 hv = __builtin_bit_cast(float2, u);
#pragma unroll
            for (int j = 0; j < 8; ++j) {
                float wj = W_s[j * 1028 + 512 + d];
                hacc[j].x += wj * hv.x;
                hacc[j].y += wj * hv.y;
            }
        }
#pragma unroll
        for (int j = 0; j < 8; ++j) {
            hacc[j].x += __shfl_xor(hacc[j].x, 32);
            hacc[j].y += __shfl_xor(hacc[j].y, 32);
        }
        if (lane < 32) {
#pragma unroll
            for (int j = 0; j < 8; ++j)
                *(float2*)&hpart[wv16 * 544 + j * 68 + 2 * s] = hacc[j];
        }
        __syncthreads();

        // ---- epilogue: reduce partials, activations, c/h update ----
        float hn = 0.f, cn = 0.f;
        int mloc = tid >> 6, b = tid & 63;
        if (tid < 128) {
            float g[4];
#pragma unroll
            for (int gi = 0; gi < 4; ++gi) {
                int j = mloc * 4 + gi;
                float v = bias_s[j];
#pragma unroll
                for (int qq = 0; qq < 4; ++qq) v += xpart[qq * 544 + j * 68 + b];
#pragma unroll
                for (int w = 0; w < 16; ++w)  v += hpart[w * 544 + j * 68 + b];
                g[gi] = v;
            }
            float ig = 1.f / (1.f + expf(-g[0]));
            float og = 1.f / (1.f + expf(-g[1]));
            float ug = tanhf(g[2]);
            float fg = 1.f / (1.f + expf(-g[3]));
            cn = ig * ug + fg * c_s[mloc * 64 + b];
            c_s[mloc * 64 + b] = cn;
            hn = og * tanhf(cn);
            // single-writer transposed h write (coherence point)
            __hip_atomic_store(&hist[(size_t)((t + 1) & 1) * 32768
                                     + (2 * wg + mloc) * 64 + b], hn,
                               __ATOMIC_RELAXED, __HIP_MEMORY_SCOPE_AGENT);
        }
        __syncthreads();   // drains hist stores before the arrive below

        // ---- arrive epoch t+2: single relaxed store, no RMW ----
        if (tid == 0) {
            __hip_atomic_store(&bar[wg], t + 2, __ATOMIC_RELAXED,
                               __HIP_MEMORY_SCOPE_AGENT);
        }

        // ---- DEFERRED out stores (off the critical path; drain next step) ----
        if (tid < 128) {
            int mg = 2 * wg + mloc;
            out[((size_t)t * BATCH + b) * MEMDIM + mg] = hn;
            if (t == T_STEPS - 1) {
                out[(size_t)T_STEPS * BATCH * MEMDIM + (size_t)b * MEMDIM + mg] = cn;
                out[(size_t)T_STEPS * BATCH * MEMDIM + (size_t)BATCH * MEMDIM
                    + (size_t)b * MEMDIM + mg] = hn;
            }
        }
    }
}

extern "C" void kernel_launch(void* const* d_in, const int* in_sizes, int n_in,
                              void* d_out, int out_size, void* d_ws, size_t ws_size,
                              hipStream_t stream) {
    (void)in_sizes; (void)n_in; (void)out_size; (void)ws_size;
    const float* inputs = (const float*)d_in[0];
    const float* h0     = (const float*)d_in[1];
    const float* c0     = (const float*)d_in[2];
    const float* W_ioux = (const float*)d_in[3];
    const float* b_ioux = (const float*)d_in[4];
    const float* W_iouh = (const float*)d_in[5];
    const float* b_iouh = (const float*)d_in[6];
    const float* W_fx   = (const float*)d_in[7];
    const float* b_fx   = (const float*)d_in[8];
    const float* W_fh   = (const float*)d_in[9];
    const float* b_fh   = (const float*)d_in[10];
    float* out = (float*)d_out;
    int*   bar = (int*)d_ws;

    const size_t smem_bytes = SMEM_FLOATS * sizeof(float);   // ~77 KB
    (void)hipFuncSetAttribute((const void*)lstm_scan,
                              hipFuncAttributeMaxDynamicSharedMemorySize,
                              (int)smem_bytes);

    // zero arrive slots (first 8KB of ws); hist needs no init
    (void)hipMemsetAsync(d_ws, 0, 8192, stream);

    void* args[] = { (void*)&inputs, (void*)&h0, (void*)&c0,
                     (void*)&W_ioux, (void*)&b_ioux, (void*)&W_iouh, (void*)&b_iouh,
                     (void*)&W_fx, (void*)&b_fx, (void*)&W_fh, (void*)&b_fh,
                     (void*)&out, (void*)&bar };

    hipError_t err = hipLaunchCooperativeKernel((const void*)lstm_scan,
                                                dim3(NWG), dim3(NT),
                                                args, smem_bytes, stream);
    if (err != hipSuccess) {
        hipLaunchKernelGGL(lstm_scan, dim3(NWG), dim3(NT), smem_bytes, stream,
                           inputs, h0, c0, W_ioux, b_ioux, W_iouh, b_iouh,
                           W_fx, b_fx, W_fh, b_fh, out, bar);
    }
}

// Round 11
// 6268.825 us; speedup vs baseline: 1.0379x; 1.0379x over previous
//
#include <hip/hip_runtime.h>
#include <math.h>

#define T_STEPS 512
#define BATCH   64
#define INDIM   512
#define MEMDIM  512
#define NWG     256
#define NT      1024

// WG wg owns mem dims {2wg,2wg+1} (8 gate rows). Weights LDS-stationary.
// NEW (R11): write-once h ring hist[513][512][64] in ws. Producer h stores
// stay sc1 (reach coherence point); consumer h loads are PLAIN CACHED float2
// (no address is ever rewritten inside one kernel execution + caches start
// invalidated at dispatch -> staleness impossible; per-XCD L2 serves 32 CUs,
// IF$ traffic drops 32x). Per-wave producer wait: wave wv16 polls only its 16
// producer WG slots (bar[16*wv16+lane]), saving one syncthreads and letting
// waves start as soon as their slice is ready. Fallback (ws too small) =
// R10 path: double-buffered hist + sc1 atomic h loads.
// out stores deferred past the arrive. x-dot hoisted above the wait.
// LDS (77KB): W_s[8][1028] | xpart[4][8][68] | hpart[16][8][68]
//             | c_s[2][64] | bias_s[8]

#define SMEM_FLOATS (8*1028 + 4*8*68 + 16*8*68 + 2*64 + 8)

extern "C" __global__ void __launch_bounds__(NT, 1)
lstm_scan(const float* __restrict__ inputs, const float* __restrict__ h0,
          const float* __restrict__ c0,
          const float* __restrict__ W_ioux, const float* __restrict__ b_ioux,
          const float* __restrict__ W_iouh, const float* __restrict__ b_iouh,
          const float* __restrict__ W_fx,   const float* __restrict__ b_fx,
          const float* __restrict__ W_fh,   const float* __restrict__ b_fh,
          float* __restrict__ out, int* __restrict__ bar, int ring)
{
    extern __shared__ float smem[];
    float* W_s    = smem;                       // [8][1028]
    float* xpart  = smem + 8*1028;              // [4][8][68]
    float* hpart  = xpart + 4*8*68;             // [16][8][68]
    float* c_s    = hpart + 16*8*68;            // [2][64]
    float* bias_s = c_s + 2*64;                 // [8]

    float* hist = (float*)(bar + 2048);         // ring [513][512][64] at ws+8KB

    const int tid  = threadIdx.x;
    const int wg   = blockIdx.x;
    const int lane = tid & 63;
    const int wv16 = tid >> 6;          // wave 0..15

    // x-dot mapping: quarter q, gate row j8, batch rows b0,b1
    const int q    = tid >> 8;
    const int r    = tid & 255;
    const int j8   = r & 7;
    const int bsub = (r >> 3) & 7;
    const int wv   = r >> 6;
    const int b0   = 16 * wv + bsub;
    const int b1   = b0 + 8;

    // h-dot mapping: wave owns dims [32*wv16, 32*wv16+32); lane=(dsub,s)
    const int s    = lane & 31;         // batch pair index
    const int dsub = lane >> 5;         // 0/1

    // ---- stage weights into LDS (once) ----
    for (int i = tid; i < 8 * 256; i += NT) {
        int row = i >> 8;
        int c4  = i & 255;
        int mloc = row >> 2, gate = row & 3;
        int mg = 2 * wg + mloc;
        const float* src;
        if (c4 < 128) {
            const float* Wx = (gate < 3) ? (W_ioux + (size_t)(gate * 512 + mg) * INDIM)
                                         : (W_fx   + (size_t)mg * INDIM);
            src = Wx + c4 * 4;
        } else {
            const float* Wh = (gate < 3) ? (W_iouh + (size_t)(gate * 512 + mg) * MEMDIM)
                                         : (W_fh   + (size_t)mg * MEMDIM);
            src = Wh + (c4 - 128) * 4;
        }
        float4 v = *(const float4*)src;
        *(float4*)&W_s[row * 1028 + c4 * 4] = v;
    }
    if (tid < 8) {
        int mloc = tid >> 2, gate = tid & 3, mg = 2 * wg + mloc;
        bias_s[tid] = (gate < 3) ? (b_ioux[gate * 512 + mg] + b_iouh[gate * 512 + mg])
                                 : (b_fx[mg] + b_fh[mg]);
    }
    if (tid < 128) {
        int mloc = tid >> 6, b = tid & 63;
        c_s[mloc * 64 + b] = c0[(size_t)b * MEMDIM + 2 * wg + mloc];
        // prologue: transpose h0 slice into hist[0] (single-writer rows)
        float hv = h0[(size_t)b * MEMDIM + 2 * wg + mloc];
        __hip_atomic_store(&hist[(2 * wg + mloc) * 64 + b], hv,
                           __ATOMIC_RELAXED, __HIP_MEMORY_SCOPE_AGENT);
    }
    __syncthreads();   // LDS ready; hist[0] stores drained (vmcnt)

    if (tid == 0) {    // arrive epoch 1
        __hip_atomic_store(&bar[wg], 1, __ATOMIC_RELAXED, __HIP_MEMORY_SCOPE_AGENT);
    }

    const float4* wrowx = (const float4*)&W_s[j8 * 1028] + q * 32;

    for (int t = 0; t < T_STEPS; ++t) {
        // ---- x-side dot (independent of h; overlaps the wait) ----
        const float4* x0p = (const float4*)(inputs + ((size_t)t * BATCH + b0) * INDIM) + q * 32;
        const float4* x1p = (const float4*)(inputs + ((size_t)t * BATCH + b1) * INDIM) + q * 32;
        float4 a0 = make_float4(0.f, 0.f, 0.f, 0.f);
        float4 a1 = make_float4(0.f, 0.f, 0.f, 0.f);
#pragma unroll 8
        for (int k = 0; k < 32; ++k) {
            float4 w  = wrowx[k];
            float4 v0 = x0p[k];
            float4 v1 = x1p[k];
            a0.x += v0.x * w.x; a0.y += v0.y * w.y; a0.z += v0.z * w.z; a0.w += v0.w * w.w;
            a1.x += v1.x * w.x; a1.y += v1.y * w.y; a1.z += v1.z * w.z; a1.w += v1.w * w.w;
        }
        xpart[q * 544 + j8 * 68 + b0] = a0.x + a0.y + a0.z + a0.w;
        xpart[q * 544 + j8 * 68 + b1] = a1.x + a1.y + a1.z + a1.w;

        // ---- per-wave wait: only the 16 producers of this wave's dim slice ----
        {
            const int need = t + 1;
            for (;;) {
                int e = 0x7fffffff;
                if (lane < 16)
                    e = __hip_atomic_load(&bar[wv16 * 16 + lane], __ATOMIC_RELAXED,
                                          __HIP_MEMORY_SCOPE_AGENT);
                if (__all(e >= need)) break;
                __builtin_amdgcn_s_sleep(1);
            }
            asm volatile("" ::: "memory");   // no load hoisting above the wait
        }

        // ---- h-side dot: wave-owned 32-dim slice, lane=batch pair ----
        float2 hacc[8];
#pragma unroll
        for (int j = 0; j < 8; ++j) { hacc[j].x = 0.f; hacc[j].y = 0.f; }

        if (ring) {   // plain cached loads from the write-once ring (L2-served)
            const float* hrow = hist + (size_t)t * 32768;
#pragma unroll 4
            for (int it = 0; it < 16; ++it) {
                int d = wv16 * 32 + it * 2 + dsub;
                float2 hv = *(const float2*)(hrow + d * 64 + 2 * s);
#pragma unroll
                for (int j = 0; j < 8; ++j) {
                    float wj = W_s[j * 1028 + 512 + d];
                    hacc[j].x += wj * hv.x;
                    hacc[j].y += wj * hv.y;
                }
            }
        } else {      // fallback (R10): sc1 atomic loads, double buffer
            const unsigned long long* hrow =
                (const unsigned long long*)(hist + (size_t)(t & 1) * 32768);
#pragma unroll 4
            for (int it = 0; it < 16; ++it) {
                int d = wv16 * 32 + it * 2 + dsub;
                unsigned long long u = __hip_atomic_load(hrow + d * 32 + s,
                                                         __ATOMIC_RELAXED,
                                                         __HIP_MEMORY_SCOPE_AGENT);
                float2 hv = __builtin_bit_cast(float2, u);
#pragma unroll
                for (int j = 0; j < 8; ++j) {
                    float wj = W_s[j * 1028 + 512 + d];
                    hacc[j].x += wj * hv.x;
                    hacc[j].y += wj * hv.y;
                }
            }
        }
#pragma unroll
        for (int j = 0; j < 8; ++j) {
            hacc[j].x += __shfl_xor(hacc[j].x, 32);
            hacc[j].y += __shfl_xor(hacc[j].y, 32);
        }
        if (lane < 32) {
#pragma unroll
            for (int j = 0; j < 8; ++j)
                *(float2*)&hpart[wv16 * 544 + j * 68 + 2 * s] = hacc[j];
        }
        __syncthreads();   // joins x-dot + all waves' hpart

        // ---- epilogue: reduce partials, activations, c/h update ----
        float hn = 0.f, cn = 0.f;
        int mloc = tid >> 6, b = tid & 63;
        if (tid < 128) {
            float g[4];
#pragma unroll
            for (int gi = 0; gi < 4; ++gi) {
                int j = mloc * 4 + gi;
                float v = bias_s[j];
#pragma unroll
                for (int qq = 0; qq < 4; ++qq) v += xpart[qq * 544 + j * 68 + b];
#pragma unroll
                for (int w = 0; w < 16; ++w)  v += hpart[w * 544 + j * 68 + b];
                g[gi] = v;
            }
            float ig = 1.f / (1.f + expf(-g[0]));
            float og = 1.f / (1.f + expf(-g[1]));
            float ug = tanhf(g[2]);
            float fg = 1.f / (1.f + expf(-g[3]));
            cn = ig * ug + fg * c_s[mloc * 64 + b];
            c_s[mloc * 64 + b] = cn;
            hn = og * tanhf(cn);
            // single-writer h write-through (must reach coherence point)
            size_t wroff = ring ? (size_t)(t + 1) * 32768 : (size_t)((t + 1) & 1) * 32768;
            __hip_atomic_store(&hist[wroff + (2 * wg + mloc) * 64 + b], hn,
                               __ATOMIC_RELAXED, __HIP_MEMORY_SCOPE_AGENT);
        }
        __syncthreads();   // drains hist stores (vmcnt0) before the arrive

        // ---- arrive epoch t+2: single relaxed store ----
        if (tid == 0) {
            __hip_atomic_store(&bar[wg], t + 2, __ATOMIC_RELAXED,
                               __HIP_MEMORY_SCOPE_AGENT);
        }

        // ---- DEFERRED out stores (off the critical path) ----
        if (tid < 128) {
            int mg = 2 * wg + mloc;
            out[((size_t)t * BATCH + b) * MEMDIM + mg] = hn;
            if (t == T_STEPS - 1) {
                out[(size_t)T_STEPS * BATCH * MEMDIM + (size_t)b * MEMDIM + mg] = cn;
                out[(size_t)T_STEPS * BATCH * MEMDIM + (size_t)BATCH * MEMDIM
                    + (size_t)b * MEMDIM + mg] = hn;
            }
        }
    }
}

extern "C" void kernel_launch(void* const* d_in, const int* in_sizes, int n_in,
                              void* d_out, int out_size, void* d_ws, size_t ws_size,
                              hipStream_t stream) {
    (void)in_sizes; (void)n_in; (void)out_size;
    const float* inputs = (const float*)d_in[0];
    const float* h0     = (const float*)d_in[1];
    const float* c0     = (const float*)d_in[2];
    const float* W_ioux = (const float*)d_in[3];
    const float* b_ioux = (const float*)d_in[4];
    const float* W_iouh = (const float*)d_in[5];
    const float* b_iouh = (const float*)d_in[6];
    const float* W_fx   = (const float*)d_in[7];
    const float* b_fx   = (const float*)d_in[8];
    const float* W_fh   = (const float*)d_in[9];
    const float* b_fh   = (const float*)d_in[10];
    float* out = (float*)d_out;
    int*   bar = (int*)d_ws;

    // ring needs 8KB flags + 513*128KB hist
    const size_t need_ring = 8192 + (size_t)513 * 32768 * 4;
    int ring = (ws_size >= need_ring) ? 1 : 0;

    const size_t smem_bytes = SMEM_FLOATS * sizeof(float);   // ~77 KB
    (void)hipFuncSetAttribute((const void*)lstm_scan,
                              hipFuncAttributeMaxDynamicSharedMemorySize,
                              (int)smem_bytes);

    // zero arrive slots (first 8KB of ws); hist needs no init
    (void)hipMemsetAsync(d_ws, 0, 8192, stream);

    void* args[] = { (void*)&inputs, (void*)&h0, (void*)&c0,
                     (void*)&W_ioux, (void*)&b_ioux, (void*)&W_iouh, (void*)&b_iouh,
                     (void*)&W_fx, (void*)&b_fx, (void*)&W_fh, (void*)&b_fh,
                     (void*)&out, (void*)&bar, (void*)&ring };

    hipError_t err = hipLaunchCooperativeKernel((const void*)lstm_scan,
                                                dim3(NWG), dim3(NT),
                                                args, smem_bytes, stream);
    if (err != hipSuccess) {
        hipLaunchKernelGGL(lstm_scan, dim3(NWG), dim3(NT), smem_bytes, stream,
                           inputs, h0, c0, W_ioux, b_ioux, W_iouh, b_iouh,
                           W_fx, b_fx, W_fh, b_fh, out, bar, ring);
    }
}